// Round 1
// baseline (1219.737 us; speedup 1.0000x reference)
//
#include <hip/hip_runtime.h>
#include <hip/hip_bf16.h>

using bf16 = __hip_bfloat16;
typedef __attribute__((ext_vector_type(8))) short bfrag;   // 8 x bf16 (4 VGPRs)
typedef __attribute__((ext_vector_type(4))) float f32x4;

#define DEVINL __device__ __forceinline__

DEVINL unsigned short f2bf(float x) {
    bf16 b = __float2bfloat16(x);
    return *reinterpret_cast<unsigned short*>(&b);
}
DEVINL float bf2f(unsigned short u) {
    bf16 b = *reinterpret_cast<bf16*>(&u);
    return __bfloat162float(b);
}

DEVINL void gload_lds16(const bf16* g, bf16* l) {
    __builtin_amdgcn_global_load_lds(
        (const __attribute__((address_space(1))) void*)g,
        (__attribute__((address_space(3))) void*)l,
        16, 0, 0);
}

// ---------------------------------------------------------------------------
// init accumulators (recon_sum, kl_sum)
// ---------------------------------------------------------------------------
__global__ void init_acc(double* acc) {
    if (threadIdx.x < 2) acc[threadIdx.x] = 0.0;
}

// ---------------------------------------------------------------------------
// transpose + cast: W[K][N] f32  ->  WT[N][K] bf16
// ---------------------------------------------------------------------------
__global__ void transpose_cast(const float* __restrict__ W, bf16* __restrict__ WT,
                               int K, int N) {
    __shared__ float tile[32][33];
    int n0 = blockIdx.x * 32, k0 = blockIdx.y * 32;
    int tx = threadIdx.x, ty0 = threadIdx.y;   // block 32 x 8
#pragma unroll
    for (int i = 0; i < 4; ++i) {
        int ty = ty0 + i * 8;
        tile[ty][tx] = W[(size_t)(k0 + ty) * N + n0 + tx];
    }
    __syncthreads();
#pragma unroll
    for (int i = 0; i < 4; ++i) {
        int ty = ty0 + i * 8;
        WT[(size_t)(n0 + ty) * K + k0 + tx] = __float2bfloat16(tile[tx][ty]);
    }
}

// ---------------------------------------------------------------------------
// gather sampled rows (circular-buffer semantics: rows <8192 come from flat
// hidden_states, else from memory) and cast to bf16
// ---------------------------------------------------------------------------
__global__ void gather_cast(const float* __restrict__ hidden,
                            const float* __restrict__ memory,
                            const int* __restrict__ idx,
                            bf16* __restrict__ samples) {
    int s = blockIdx.x;
    int r = idx[s];
    const float* src = (r < 8192) ? hidden + (size_t)r * 4096
                                  : memory + (size_t)r * 4096;
    unsigned short* dst = (unsigned short*)(samples + (size_t)s * 4096);
#pragma unroll
    for (int c = threadIdx.x * 4; c < 4096; c += 1024) {
        float4 v = *(const float4*)(src + c);
        ushort4 o;
        o.x = f2bf(v.x); o.y = f2bf(v.y); o.z = f2bf(v.z); o.w = f2bf(v.w);
        *(ushort4*)(dst + c) = o;
    }
}

// ---------------------------------------------------------------------------
// GEMM  C[M,N] = A[M,K] @ BT[N,K]^T  (+bias, fused epilogue)
// 128x128 tile, BK=32, 4 waves (2x2), 16x16x32 bf16 MFMA, double-buffered LDS,
// global_load_lds width 16, XOR swizzle blk^=(row&3) applied BOTH sides.
// EPI: 0 = gelu(exact) -> bf16 ; 1 = store bf16 ; 3 = recon MSE reduce
// ---------------------------------------------------------------------------
template <int EPI>
__global__ __launch_bounds__(256, 2)
void gemm_bt(const bf16* __restrict__ A, const bf16* __restrict__ BT,
             const float* __restrict__ bias, bf16* __restrict__ C,
             const bf16* __restrict__ S, double* __restrict__ accum,
             int M, int N, int K) {
    __shared__ __align__(16) bf16 lds[2][2][128 * 32];

    const int tid  = threadIdx.x;
    const int lane = tid & 63;
    const int wave = tid >> 6;
    const int wr   = wave >> 1;
    const int wc   = wave & 1;
    const int m0   = blockIdx.y * 128;
    const int n0   = blockIdx.x * 128;

    auto stage = [&](int buf, int kt) {
        const size_t kbase = (size_t)kt * 32;
#pragma unroll
        for (int i = 0; i < 2; ++i) {
            int r  = i * 64 + (tid >> 2);
            int b  = tid & 3;
            int bg = b ^ (r & 3);                 // pre-swizzled global source
            gload_lds16(A + (size_t)(m0 + r) * K + kbase + bg * 8,
                        &lds[buf][0][(i * 256 + tid) * 8]);
            gload_lds16(BT + (size_t)(n0 + r) * K + kbase + bg * 8,
                        &lds[buf][1][(i * 256 + tid) * 8]);
        }
    };

    auto rdfrag = [&](const bf16* base, int row) -> bfrag {
        int g = lane >> 4;
        int e = row * 32 + ((g ^ (row & 3)) << 3);  // swizzled read
        return *(const bfrag*)(base + e);
    };

    f32x4 acc[4][4] = {};

    const int nk = K >> 5;
    stage(0, 0);
    __syncthreads();
    int cur = 0;
    for (int kt = 0; kt < nk; ++kt) {
        if (kt + 1 < nk) stage(cur ^ 1, kt + 1);
        bfrag af[4], bfv[4];
#pragma unroll
        for (int m = 0; m < 4; ++m)
            af[m] = rdfrag(lds[cur][0], wr * 64 + m * 16 + (lane & 15));
#pragma unroll
        for (int n = 0; n < 4; ++n)
            bfv[n] = rdfrag(lds[cur][1], wc * 64 + n * 16 + (lane & 15));
#pragma unroll
        for (int m = 0; m < 4; ++m)
#pragma unroll
            for (int n = 0; n < 4; ++n)
                acc[m][n] = __builtin_amdgcn_mfma_f32_16x16x32_bf16(
                    af[m], bfv[n], acc[m][n], 0, 0, 0);
        __syncthreads();
        cur ^= 1;
    }

    // epilogue: C/D layout col=lane&15, row=(lane>>4)*4+j  [m89-verified]
    float lsum = 0.f;
#pragma unroll
    for (int m = 0; m < 4; ++m) {
        int row0 = m0 + wr * 64 + m * 16 + (lane >> 4) * 4;
#pragma unroll
        for (int n = 0; n < 4; ++n) {
            int col = n0 + wc * 64 + n * 16 + (lane & 15);
            float bv = bias[col];
#pragma unroll
            for (int j = 0; j < 4; ++j) {
                float v  = acc[m][n][j] + bv;
                int row  = row0 + j;
                if (EPI == 0) {
                    float ge = 0.5f * v * (1.f + erff(v * 0.70710678118f));
                    C[(size_t)row * N + col] = __float2bfloat16(ge);
                } else if (EPI == 1) {
                    C[(size_t)row * N + col] = __float2bfloat16(v);
                } else {
                    float d = v - __bfloat162float(S[(size_t)row * N + col]);
                    lsum += d * d;
                }
            }
        }
    }

    if (EPI == 3) {
        __shared__ float red[4];
        float v = lsum;
#pragma unroll
        for (int o = 32; o > 0; o >>= 1) v += __shfl_down(v, o);
        if (lane == 0) red[wave] = v;
        __syncthreads();
        if (tid == 0) {
            double t = (double)red[0] + (double)red[1] +
                       (double)red[2] + (double)red[3];
            atomicAdd(accum, t);
        }
    }
}

// ---------------------------------------------------------------------------
// reparameterization + KL partial sums
// enc[s, 0:1024]=mu, enc[s,1024:2048]=logvar ; z = mu + exp(0.5 lv)*eps
// kl elementwise: 1 + lv - mu^2 - exp(lv)  (summed; finalize applies -0.5)
// ---------------------------------------------------------------------------
__global__ void z_kl_kernel(const bf16* __restrict__ enc,
                            const float* __restrict__ eps,
                            bf16* __restrict__ z, double* __restrict__ acc) {
    int s = blockIdx.x;
    int c = threadIdx.x * 4;
    const unsigned short* mup = (const unsigned short*)(enc + (size_t)s * 2048 + c);
    const unsigned short* lvp = (const unsigned short*)(enc + (size_t)s * 2048 + 1024 + c);
    ushort4 muu = *(const ushort4*)mup;
    ushort4 lvu = *(const ushort4*)lvp;
    float4 ev   = *(const float4*)(eps + (size_t)s * 1024 + c);

    float kl = 0.f;
    ushort4 zo;
    {
        float mu = bf2f(muu.x), lv = bf2f(lvu.x), el = expf(lv);
        zo.x = f2bf(mu + sqrtf(el) * ev.x);
        kl += 1.f + lv - mu * mu - el;
    }
    {
        float mu = bf2f(muu.y), lv = bf2f(lvu.y), el = expf(lv);
        zo.y = f2bf(mu + sqrtf(el) * ev.y);
        kl += 1.f + lv - mu * mu - el;
    }
    {
        float mu = bf2f(muu.z), lv = bf2f(lvu.z), el = expf(lv);
        zo.z = f2bf(mu + sqrtf(el) * ev.z);
        kl += 1.f + lv - mu * mu - el;
    }
    {
        float mu = bf2f(muu.w), lv = bf2f(lvu.w), el = expf(lv);
        zo.w = f2bf(mu + sqrtf(el) * ev.w);
        kl += 1.f + lv - mu * mu - el;
    }
    *(ushort4*)((unsigned short*)(z + (size_t)s * 1024 + c)) = zo;

    __shared__ float red[4];
    float v = kl;
#pragma unroll
    for (int o = 32; o > 0; o >>= 1) v += __shfl_down(v, o);
    int lane = threadIdx.x & 63, wave = threadIdx.x >> 6;
    if (lane == 0) red[wave] = v;
    __syncthreads();
    if (threadIdx.x == 0) {
        double t = (double)red[0] + (double)red[1] +
                   (double)red[2] + (double)red[3];
        atomicAdd(acc + 1, t);
    }
}

// ---------------------------------------------------------------------------
// out = recon_sum / (16384*4096) + 0.001 * (-0.5 * kl_sum)
// ---------------------------------------------------------------------------
__global__ void finalize_kernel(const double* __restrict__ acc,
                                float* __restrict__ out) {
    if (threadIdx.x == 0)
        out[0] = (float)(acc[0] * (1.0 / (16384.0 * 4096.0)) - 0.0005 * acc[1]);
}

// ---------------------------------------------------------------------------
extern "C" void kernel_launch(void* const* d_in, const int* in_sizes, int n_in,
                              void* d_out, int out_size, void* d_ws, size_t ws_size,
                              hipStream_t stream) {
    const float* hidden = (const float*)d_in[0];
    const float* memory = (const float*)d_in[1];
    const int*   idx    = (const int*)d_in[2];
    const float* eps    = (const float*)d_in[3];
    const float* W1     = (const float*)d_in[4];
    const float* b1     = (const float*)d_in[5];
    const float* W2     = (const float*)d_in[6];
    const float* b2     = (const float*)d_in[7];
    const float* Wd1    = (const float*)d_in[8];
    const float* bd1    = (const float*)d_in[9];
    const float* Wd2    = (const float*)d_in[10];
    const float* bd2    = (const float*)d_in[11];

    char* ws = (char*)d_ws;
    double* acc   = (double*)ws;                                   // 16 B
    bf16* samples = (bf16*)(ws + 256);                             // 16384x4096
    bf16* h       = samples + (size_t)16384 * 4096;                // 16384x2048 (reused for hd)
    bf16* enc     = h       + (size_t)16384 * 2048;                // 16384x2048
    bf16* z       = enc     + (size_t)16384 * 2048;                // 16384x1024
    bf16* W1T     = z       + (size_t)16384 * 1024;                // 2048x4096
    bf16* W2T     = W1T     + (size_t)2048 * 4096;                 // 2048x2048
    bf16* Wd1T    = W2T     + (size_t)2048 * 2048;                 // 2048x1024
    bf16* Wd2T    = Wd1T    + (size_t)2048 * 1024;                 // 4096x2048

    init_acc<<<1, 64, 0, stream>>>(acc);

    dim3 tb(32, 8);
    transpose_cast<<<dim3(2048 / 32, 4096 / 32), tb, 0, stream>>>(W1, W1T, 4096, 2048);
    transpose_cast<<<dim3(2048 / 32, 2048 / 32), tb, 0, stream>>>(W2, W2T, 2048, 2048);
    transpose_cast<<<dim3(2048 / 32, 1024 / 32), tb, 0, stream>>>(Wd1, Wd1T, 1024, 2048);
    transpose_cast<<<dim3(4096 / 32, 2048 / 32), tb, 0, stream>>>(Wd2, Wd2T, 2048, 4096);

    gather_cast<<<16384, 256, 0, stream>>>(hidden, memory, idx, samples);

    // h = gelu(samples @ W1 + b1)
    gemm_bt<0><<<dim3(16, 128), 256, 0, stream>>>(samples, W1T, b1, h, nullptr, nullptr,
                                                  16384, 2048, 4096);
    // enc = h @ W2 + b2
    gemm_bt<1><<<dim3(16, 128), 256, 0, stream>>>(h, W2T, b2, enc, nullptr, nullptr,
                                                  16384, 2048, 2048);
    // z = mu + exp(0.5 lv) * eps ; kl partials
    z_kl_kernel<<<16384, 256, 0, stream>>>(enc, eps, z, acc);
    // hd = gelu(z @ Wd1 + bd1)   (reuses h buffer)
    gemm_bt<0><<<dim3(16, 128), 256, 0, stream>>>(z, Wd1T, bd1, h, nullptr, nullptr,
                                                  16384, 2048, 1024);
    // rec = hd @ Wd2 + bd2 ; fused recon MSE vs samples
    gemm_bt<3><<<dim3(32, 128), 256, 0, stream>>>(h, Wd2T, bd2, nullptr, samples, acc,
                                                  16384, 4096, 2048);

    finalize_kernel<<<1, 64, 0, stream>>>(acc, (float*)d_out);
}

// Round 2
// 1082.397 us; speedup vs baseline: 1.1269x; 1.1269x over previous
//
#include <hip/hip_runtime.h>
#include <hip/hip_bf16.h>

using bf16 = __hip_bfloat16;
typedef __attribute__((ext_vector_type(8))) short bfrag;   // 8 x bf16 (4 VGPRs)
typedef __attribute__((ext_vector_type(4))) float f32x4;

#define DEVINL __device__ __forceinline__

DEVINL unsigned short f2bf(float x) {
    bf16 b = __float2bfloat16(x);
    return *reinterpret_cast<unsigned short*>(&b);
}
DEVINL float bf2f(unsigned short u) {
    bf16 b = *reinterpret_cast<bf16*>(&u);
    return __bfloat162float(b);
}

DEVINL void gload_lds16(const bf16* g, bf16* l) {
    __builtin_amdgcn_global_load_lds(
        (const __attribute__((address_space(1))) void*)g,
        (__attribute__((address_space(3))) void*)l,
        16, 0, 0);
}

// ---------------------------------------------------------------------------
__global__ void init_acc(double* acc) {
    if (threadIdx.x < 2) acc[threadIdx.x] = 0.0;
}

// ---------------------------------------------------------------------------
// transpose + cast: W[K][N] f32 -> WT[N][K] bf16
// ---------------------------------------------------------------------------
__global__ void transpose_cast(const float* __restrict__ W, bf16* __restrict__ WT,
                               int K, int N) {
    __shared__ float tile[32][33];
    int n0 = blockIdx.x * 32, k0 = blockIdx.y * 32;
    int tx = threadIdx.x, ty0 = threadIdx.y;   // block 32 x 8
#pragma unroll
    for (int i = 0; i < 4; ++i) {
        int ty = ty0 + i * 8;
        tile[ty][tx] = W[(size_t)(k0 + ty) * N + n0 + tx];
    }
    __syncthreads();
#pragma unroll
    for (int i = 0; i < 4; ++i) {
        int ty = ty0 + i * 8;
        WT[(size_t)(n0 + ty) * K + k0 + tx] = __float2bfloat16(tile[tx][ty]);
    }
}

// ---------------------------------------------------------------------------
// gather sampled rows (circular-buffer: rows <8192 come from hidden flat)
// ---------------------------------------------------------------------------
__global__ void gather_cast(const float* __restrict__ hidden,
                            const float* __restrict__ memory,
                            const int* __restrict__ idx,
                            bf16* __restrict__ samples) {
    int s = blockIdx.x;
    int r = idx[s];
    const float* src = (r < 8192) ? hidden + (size_t)r * 4096
                                  : memory + (size_t)r * 4096;
    unsigned short* dst = (unsigned short*)(samples + (size_t)s * 4096);
#pragma unroll
    for (int c = threadIdx.x * 4; c < 4096; c += 1024) {
        float4 v = *(const float4*)(src + c);
        ushort4 o;
        o.x = f2bf(v.x); o.y = f2bf(v.y); o.z = f2bf(v.z); o.w = f2bf(v.w);
        *(ushort4*)(dst + c) = o;
    }
}

// ---------------------------------------------------------------------------
// GEMM  C[M,N] = A[M,K] @ BT[N,K]^T  (+bias, fused epilogue)
// 256x256 tile, BK=32, 8 waves (2M x 4N), 4-deep LDS ring (128 KiB),
// counted vmcnt(8) — loads for 2 future K-tiles stay in flight across the
// single per-iter barrier. XOR swizzle blk^=(row>>1)&3 both sides (2-way,
// free). XCD-chunked bijective work decode (n-major inside an XCD).
// EPI: 0 = gelu(exact)->bf16 ; 1 = store bf16 ; 3 = recon MSE reduce
// ---------------------------------------------------------------------------
template <int EPI>
__global__ __launch_bounds__(512, 2)
void gemm256(const bf16* __restrict__ A, const bf16* __restrict__ BT,
             const float* __restrict__ bias, bf16* __restrict__ C,
             const bf16* __restrict__ S, double* __restrict__ accum,
             int M, int N, int K, int MT) {
    // [ring buf][A=0/B=1][256 rows x 32 k]  = 4*2*8192*2B = 128 KiB
    __shared__ __align__(16) bf16 lds[4][2][256 * 32];

    const int tid  = threadIdx.x;
    const int lane = tid & 63;
    const int wave = tid >> 6;      // 0..7
    const int wr   = wave >> 2;     // 0..1  (M half)
    const int wc   = wave & 3;      // 0..3  (N quarter)

    // XCD-aware bijective chunked decode (gridDim.x % 8 == 0 for all calls)
    const int nwg  = gridDim.x;
    const int cpx  = nwg >> 3;
    const int work = (blockIdx.x & 7) * cpx + (blockIdx.x >> 3);
    const int ntile = work / MT;
    const int mtile = work - ntile * MT;
    const int m0 = mtile * 256;
    const int n0 = ntile * 256;

    auto stage = [&](int buf, int kt) {
        const size_t kb = (size_t)kt * 32;
        const int r = tid >> 2;          // 0..127
        const int b = tid & 3;
#pragma unroll
        for (int i = 0; i < 2; ++i) {
            int row = i * 128 + r;
            int bg  = b ^ ((row >> 1) & 3);          // pre-swizzled source
            gload_lds16(A + (size_t)(m0 + row) * K + kb + (size_t)bg * 8,
                        &lds[buf][0][row * 32 + b * 8]);   // linear dest
        }
#pragma unroll
        for (int i = 0; i < 2; ++i) {
            int row = i * 128 + r;
            int bg  = b ^ ((row >> 1) & 3);
            gload_lds16(BT + (size_t)(n0 + row) * K + kb + (size_t)bg * 8,
                        &lds[buf][1][row * 32 + b * 8]);
        }
    };

    const int g = lane >> 4;            // k-group of the MFMA fragment
    auto rdA = [&](int buf, int m) -> bfrag {
        int row = wr * 128 + m * 16 + (lane & 15);
        int e   = row * 32 + ((g ^ ((row >> 1) & 3)) << 3);   // swizzled read
        return *(const bfrag*)&lds[buf][0][e];
    };
    auto rdB = [&](int buf, int n) -> bfrag {
        int row = wc * 64 + n * 16 + (lane & 15);
        int e   = row * 32 + ((g ^ ((row >> 1) & 3)) << 3);
        return *(const bfrag*)&lds[buf][1][e];
    };

    f32x4 acc[8][4] = {};

    const int nk = K >> 5;              // >= 32 for all calls
    stage(0, 0); stage(1, 1); stage(2, 2);
    asm volatile("s_waitcnt vmcnt(8)" ::: "memory");   // buffer 0 landed
    __builtin_amdgcn_s_barrier();

    for (int t = 0; t < nk; ++t) {
        const int cb = t & 3;
        bfrag af[8], bfv[4];
#pragma unroll
        for (int m = 0; m < 8; ++m) af[m] = rdA(cb, m);
#pragma unroll
        for (int n = 0; n < 4; ++n) bfv[n] = rdB(cb, n);
        if (t + 3 < nk) stage((t + 3) & 3, t + 3);     // 3 tiles ahead
        asm volatile("s_waitcnt lgkmcnt(0)" ::: "memory");
        __builtin_amdgcn_sched_barrier(0);             // rule #18
        __builtin_amdgcn_s_setprio(1);
#pragma unroll
        for (int m = 0; m < 8; ++m)
#pragma unroll
            for (int n = 0; n < 4; ++n)
                acc[m][n] = __builtin_amdgcn_mfma_f32_16x16x32_bf16(
                    af[m], bfv[n], acc[m][n], 0, 0, 0);
        __builtin_amdgcn_s_setprio(0);
        __builtin_amdgcn_sched_barrier(0);
        // counted wait: buffer t+1 complete; newer buffers stay in flight
        if (t + 3 < nk)      asm volatile("s_waitcnt vmcnt(8)" ::: "memory");
        else if (t + 2 < nk) asm volatile("s_waitcnt vmcnt(4)" ::: "memory");
        else if (t + 1 < nk) asm volatile("s_waitcnt vmcnt(0)" ::: "memory");
        __builtin_amdgcn_s_barrier();
    }

    // epilogue: C/D layout col=lane&15, row=(lane>>4)*4+j  [m89-verified]
    float lsum = 0.f;
#pragma unroll
    for (int m = 0; m < 8; ++m) {
        int row0 = m0 + wr * 128 + m * 16 + (lane >> 4) * 4;
#pragma unroll
        for (int n = 0; n < 4; ++n) {
            int col = n0 + wc * 64 + n * 16 + (lane & 15);
            float bv = bias[col];
#pragma unroll
            for (int j = 0; j < 4; ++j) {
                float v  = acc[m][n][j] + bv;
                int row  = row0 + j;
                if (EPI == 0) {
                    float ge = 0.5f * v * (1.f + erff(v * 0.70710678118f));
                    C[(size_t)row * N + col] = __float2bfloat16(ge);
                } else if (EPI == 1) {
                    C[(size_t)row * N + col] = __float2bfloat16(v);
                } else {
                    float d = v - __bfloat162float(S[(size_t)row * N + col]);
                    lsum += d * d;
                }
            }
        }
    }

    if (EPI == 3) {
        __shared__ float red[8];
        float v = lsum;
#pragma unroll
        for (int o = 32; o > 0; o >>= 1) v += __shfl_down(v, o);
        if (lane == 0) red[wave] = v;
        __syncthreads();
        if (tid == 0) {
            double t = 0.0;
#pragma unroll
            for (int w = 0; w < 8; ++w) t += (double)red[w];
            atomicAdd(accum, t);
        }
    }
}

// ---------------------------------------------------------------------------
// reparameterization + KL partial sums
// ---------------------------------------------------------------------------
__global__ void z_kl_kernel(const bf16* __restrict__ enc,
                            const float* __restrict__ eps,
                            bf16* __restrict__ z, double* __restrict__ acc) {
    int s = blockIdx.x;
    int c = threadIdx.x * 4;
    ushort4 muu = *(const ushort4*)((const unsigned short*)(enc + (size_t)s * 2048 + c));
    ushort4 lvu = *(const ushort4*)((const unsigned short*)(enc + (size_t)s * 2048 + 1024 + c));
    float4 ev   = *(const float4*)(eps + (size_t)s * 1024 + c);

    float kl = 0.f;
    ushort4 zo;
    {
        float mu = bf2f(muu.x), lv = bf2f(lvu.x), el = expf(lv);
        zo.x = f2bf(mu + sqrtf(el) * ev.x);
        kl += 1.f + lv - mu * mu - el;
    }
    {
        float mu = bf2f(muu.y), lv = bf2f(lvu.y), el = expf(lv);
        zo.y = f2bf(mu + sqrtf(el) * ev.y);
        kl += 1.f + lv - mu * mu - el;
    }
    {
        float mu = bf2f(muu.z), lv = bf2f(lvu.z), el = expf(lv);
        zo.z = f2bf(mu + sqrtf(el) * ev.z);
        kl += 1.f + lv - mu * mu - el;
    }
    {
        float mu = bf2f(muu.w), lv = bf2f(lvu.w), el = expf(lv);
        zo.w = f2bf(mu + sqrtf(el) * ev.w);
        kl += 1.f + lv - mu * mu - el;
    }
    *(ushort4*)((unsigned short*)(z + (size_t)s * 1024 + c)) = zo;

    __shared__ float red[4];
    float v = kl;
#pragma unroll
    for (int o = 32; o > 0; o >>= 1) v += __shfl_down(v, o);
    int lane = threadIdx.x & 63, wave = threadIdx.x >> 6;
    if (lane == 0) red[wave] = v;
    __syncthreads();
    if (threadIdx.x == 0) {
        double t = (double)red[0] + (double)red[1] +
                   (double)red[2] + (double)red[3];
        atomicAdd(acc + 1, t);
    }
}

// ---------------------------------------------------------------------------
__global__ void finalize_kernel(const double* __restrict__ acc,
                                float* __restrict__ out) {
    if (threadIdx.x == 0)
        out[0] = (float)(acc[0] * (1.0 / (16384.0 * 4096.0)) - 0.0005 * acc[1]);
}

// ---------------------------------------------------------------------------
extern "C" void kernel_launch(void* const* d_in, const int* in_sizes, int n_in,
                              void* d_out, int out_size, void* d_ws, size_t ws_size,
                              hipStream_t stream) {
    const float* hidden = (const float*)d_in[0];
    const float* memory = (const float*)d_in[1];
    const int*   idx    = (const int*)d_in[2];
    const float* eps    = (const float*)d_in[3];
    const float* W1     = (const float*)d_in[4];
    const float* b1     = (const float*)d_in[5];
    const float* W2     = (const float*)d_in[6];
    const float* b2     = (const float*)d_in[7];
    const float* Wd1    = (const float*)d_in[8];
    const float* bd1    = (const float*)d_in[9];
    const float* Wd2    = (const float*)d_in[10];
    const float* bd2    = (const float*)d_in[11];

    char* ws = (char*)d_ws;
    double* acc   = (double*)ws;                                   // 16 B
    bf16* samples = (bf16*)(ws + 256);                             // 16384x4096
    bf16* h       = samples + (size_t)16384 * 4096;                // 16384x2048 (reused for hd)
    bf16* enc     = h       + (size_t)16384 * 2048;                // 16384x2048
    bf16* z       = enc     + (size_t)16384 * 2048;                // 16384x1024
    bf16* W1T     = z       + (size_t)16384 * 1024;                // 2048x4096
    bf16* W2T     = W1T     + (size_t)2048 * 4096;                 // 2048x2048
    bf16* Wd1T    = W2T     + (size_t)2048 * 2048;                 // 2048x1024
    bf16* Wd2T    = Wd1T    + (size_t)2048 * 1024;                 // 4096x2048

    init_acc<<<1, 64, 0, stream>>>(acc);

    dim3 tb(32, 8);
    transpose_cast<<<dim3(2048 / 32, 4096 / 32), tb, 0, stream>>>(W1, W1T, 4096, 2048);
    transpose_cast<<<dim3(2048 / 32, 2048 / 32), tb, 0, stream>>>(W2, W2T, 2048, 2048);
    transpose_cast<<<dim3(2048 / 32, 1024 / 32), tb, 0, stream>>>(Wd1, Wd1T, 1024, 2048);
    transpose_cast<<<dim3(4096 / 32, 2048 / 32), tb, 0, stream>>>(Wd2, Wd2T, 2048, 4096);

    gather_cast<<<16384, 256, 0, stream>>>(hidden, memory, idx, samples);

    // h = gelu(samples @ W1 + b1)          M=16384 N=2048 K=4096
    gemm256<0><<<512, 512, 0, stream>>>(samples, W1T, b1, h, nullptr, nullptr,
                                        16384, 2048, 4096, 64);
    // enc = h @ W2 + b2                    K=2048
    gemm256<1><<<512, 512, 0, stream>>>(h, W2T, b2, enc, nullptr, nullptr,
                                        16384, 2048, 2048, 64);
    // z = mu + exp(0.5 lv) * eps ; kl partials
    z_kl_kernel<<<16384, 256, 0, stream>>>(enc, eps, z, acc);
    // hd = gelu(z @ Wd1 + bd1)             K=1024 (reuses h buffer)
    gemm256<0><<<512, 512, 0, stream>>>(z, Wd1T, bd1, h, nullptr, nullptr,
                                        16384, 2048, 1024, 64);
    // rec = hd @ Wd2 + bd2 ; fused recon MSE vs samples   N=4096 K=2048
    gemm256<3><<<1024, 512, 0, stream>>>(h, Wd2T, bd2, nullptr, samples, acc,
                                         16384, 4096, 2048, 64);

    finalize_kernel<<<1, 64, 0, stream>>>(acc, (float*)d_out);
}